// Round 6
// baseline (222.125 us; speedup 1.0000x reference)
//
#include <hip/hip_runtime.h>

typedef _Float16 half_t;
typedef half_t f16x8 __attribute__((ext_vector_type(8)));
typedef float f32x4 __attribute__((ext_vector_type(4)));

#define LOG2E 1.44269504088896340736f

// Problem dims (fixed)
#define NROWS 65536
#define DIN   64
#define NCTRS 1024
#define DOUT  256

// Workspace layout (bytes). ONE FRAGMENT = 64 lanes x 16 B = 1024 B.
// Cswz: QK B-frags, fid = c*4 + ct*2 + kt : 128 frags (center order natural)
// Vswz: PV B-frags, fid = c*16 + u : 512 frags, CENTER-INTERLEAVED k order:
//       k-index kk within chunk maps to center (kk>>1) + 16*(kk&1), so the
//       softmax's (p0,p1) pair for lane lm lands at adjacent kk = 2*lm, 2*lm+1
//       -> single packed b32 LDS store for P.
// csq2: 1024 floats = (sum_d ctrs^2 s) * LOG2E
#define CSWZ_OFF 0
#define CSWZ_BYTES (128 * 1024)
#define VSWZ_OFF (CSWZ_OFF + CSWZ_BYTES)            // 131072
#define VSWZ_BYTES (512 * 1024)
#define CSQ_OFF  (VSWZ_OFF + VSWZ_BYTES)            // 655360; end 659456

// ---------------------------------------------------------------------------
// Precompute, grid 256 (was 32 -> occupancy-starved): block bid = c*8 + sl.
// Each block: V-slice transpose for chunk c, cols [sl*32, sl*32+32).
// sl==0 additionally builds Cswz frags for c; sl==1 builds csq2 for c.
// Fragment layout (A/B symmetric): lane holds [idx=lane&15][k=8*(lane>>4)+j].
// ---------------------------------------------------------------------------
__global__ __launch_bounds__(256) void precompute_kernel(
    const float* __restrict__ ctrs, const float* __restrict__ values,
    const float* __restrict__ s, char* __restrict__ ws) {
  half_t* Cswz = (half_t*)(ws + CSWZ_OFF);
  half_t* Vswz = (half_t*)(ws + VSWZ_OFF);
  float* csq2 = (float*)(ws + CSQ_OFF);

  __shared__ half_t Vt[32 * 34];  // 32 centers x 32 cols, pad 34

  const int tid = threadIdx.x, bid = blockIdx.x;
  const int c = bid >> 3, sl = bid & 7;
  const int w = tid >> 6, l = tid & 63, l4 = l >> 4, lm = l & 15;

  // coalesced tile load: centers c*32.., cols sl*32..
  for (int i = tid; i < 1024; i += 256) {
    int r = i >> 5, cc = i & 31;
    Vt[r * 34 + cc] = (half_t)values[(c * 32 + r) * DOUT + sl * 32 + cc];
  }
  if (sl == 0) {  // Cswz frag f = c*4 + w; ct = w>>1, kt = w&1
    int ct = w >> 1, kt = w & 1;
    const float* src = ctrs + (c * 32 + ct * 16 + lm) * DIN + kt * 32 + l4 * 8;
    f16x8 v;
#pragma unroll
    for (int j = 0; j < 8; ++j) v[j] = (half_t)src[j];
    *(f16x8*)(Cswz + ((c * 4 + w) * 64 + l) * 8) = v;
  }
  if (sl == 1 && tid < 32) {
    int k = c * 32 + tid;
    float acc = 0.0f;
    for (int d = 0; d < DIN; ++d) {
      float cv = ctrs[k * DIN + d];
      acc = fmaf(cv * cv, s[d], acc);
    }
    csq2[k] = acc * LOG2E;
  }
  __syncthreads();

  // V frags u = sl*2 + w for w<2, k order interleaved
  if (w < 2) {
    f16x8 v;
#pragma unroll
    for (int j = 0; j < 8; ++j) {
      int kk = l4 * 8 + j;
      int ctr = (kk >> 1) + ((kk & 1) << 4);  // interleave: even kk->ct0, odd->ct1
      v[j] = Vt[ctr * 34 + w * 16 + lm];
    }
    *(f16x8*)(Vswz + ((c * 16 + sl * 2 + w) * 64 + l) * 8) = v;
  }
}

// ---------------------------------------------------------------------------
// Fused kernel: ONE WAVE PER BLOCK (64 threads), 64 rows x 128 cols per wave,
// online softmax (R1-proven), zero barriers, operands direct from L2 (R4-
// proven). A-frags parked in wave-private LDS to keep VGPR <= 256 (2 w/SIMD).
// scores = (2*cross - csq)*log2e  (x^2 term cancels in softmax).
// ---------------------------------------------------------------------------
__global__ __launch_bounds__(64, 2) void attn_kernel(
    const float* __restrict__ x, const float* __restrict__ s,
    const char* __restrict__ ws, float* __restrict__ out) {
  const half_t* Cswz = (const half_t*)(ws + CSWZ_OFF);
  const half_t* Vswz = (const half_t*)(ws + VSWZ_OFF);
  const float* csq2 = (const float*)(ws + CSQ_OFF);
  const f16x8* cbase = (const f16x8*)Cswz;
  const f16x8* vbase = (const f16x8*)Vswz;

  __shared__ half_t Alds[8 * 64 * 8];  // 8 A-frags x 1 KB = 8 KB
  __shared__ half_t Plds[64 * 40];     // P 64 rows x 32 (+8 pad) = 5 KB

  const int l = threadIdx.x, l4 = l >> 4, lm = l & 15;
  const int rg = blockIdx.x >> 1, hb = blockIdx.x & 1;  // hb = col half
  const int rowbase = rg * 64;

  // ---- A fragments (x*s -> f16) -> wave-private LDS (saves 32 VGPRs)
#pragma unroll
  for (int rt = 0; rt < 4; ++rt) {
#pragma unroll
    for (int kt = 0; kt < 2; ++kt) {
      int din = kt * 32 + l4 * 8;
      const float* src = x + (rowbase + rt * 16 + lm) * DIN + din;
      f16x8 a;
#pragma unroll
      for (int j = 0; j < 8; ++j) a[j] = (half_t)(src[j] * s[din + j]);
      *(f16x8*)(Alds + ((rt * 2 + kt) * 64 + l) * 8) = a;
    }
  }

  // ---- all-ones B column tile (col 0), lane-constant
  f16x8 ones;
#pragma unroll
  for (int j = 0; j < 8; ++j) ones[j] = (lm == 0) ? (half_t)1.0f : (half_t)0.0f;

  // ---- accumulators
  f32x4 O[4][8];
  f32x4 L[4];
  float m[4][4];
#pragma unroll
  for (int rt = 0; rt < 4; ++rt) {
    L[rt] = (f32x4){0.f, 0.f, 0.f, 0.f};
#pragma unroll
    for (int u = 0; u < 8; ++u) O[rt][u] = (f32x4){0.f, 0.f, 0.f, 0.f};
#pragma unroll
    for (int j = 0; j < 4; ++j) m[rt][j] = -1e30f;
  }

  for (int c = 0; c < 32; ++c) {
    // ---- chunk operand loads (L2-resident); vb issued early, used ~700cyc later
    f16x8 b0 = cbase[(c * 4 + 0) * 64 + l];
    f16x8 b1 = cbase[(c * 4 + 1) * 64 + l];
    f16x8 b2 = cbase[(c * 4 + 2) * 64 + l];
    f16x8 b3 = cbase[(c * 4 + 3) * 64 + l];
    float cs0 = csq2[c * 32 + lm], cs1 = csq2[c * 32 + 16 + lm];
    f16x8 vb[8];
#pragma unroll
    for (int u = 0; u < 8; ++u) vb[u] = vbase[(c * 16 + hb * 8 + u) * 64 + l];

#pragma unroll
    for (int rt = 0; rt < 4; ++rt) {
      // ---- QK: S[16 rows][32 centers], K = 64
      f16x8 a0 = *(const f16x8*)(Alds + ((rt * 2 + 0) * 64 + l) * 8);
      f16x8 a1 = *(const f16x8*)(Alds + ((rt * 2 + 1) * 64 + l) * 8);
      f32x4 acc0 = {0.f, 0.f, 0.f, 0.f}, acc1 = {0.f, 0.f, 0.f, 0.f};
      acc0 = __builtin_amdgcn_mfma_f32_16x16x32_f16(a0, b0, acc0, 0, 0, 0);
      acc0 = __builtin_amdgcn_mfma_f32_16x16x32_f16(a1, b1, acc0, 0, 0, 0);
      acc1 = __builtin_amdgcn_mfma_f32_16x16x32_f16(a0, b2, acc1, 0, 0, 0);
      acc1 = __builtin_amdgcn_mfma_f32_16x16x32_f16(a1, b3, acc1, 0, 0, 0);

      // ---- online softmax for this 16-row tile (rows in 16-lane groups)
#pragma unroll
      for (int j = 0; j < 4; ++j) {
        float s20 = fmaf(acc0[j], 2.0f * LOG2E, -cs0);
        float s21 = fmaf(acc1[j], 2.0f * LOG2E, -cs1);
        float mc = fmaxf(s20, s21);
        mc = fmaxf(mc, __shfl_xor(mc, 1));
        mc = fmaxf(mc, __shfl_xor(mc, 2));
        mc = fmaxf(mc, __shfl_xor(mc, 4));
        mc = fmaxf(mc, __shfl_xor(mc, 8));
        float mn = fmaxf(m[rt][j], mc);
        float al = __builtin_amdgcn_exp2f(m[rt][j] - mn);
        m[rt][j] = mn;
        L[rt][j] *= al;
#pragma unroll
        for (int u = 0; u < 8; ++u) O[rt][u][j] *= al;
        float p0 = __builtin_amdgcn_exp2f(s20 - mn);  // center lm   -> kk=2*lm
        float p1 = __builtin_amdgcn_exp2f(s21 - mn);  // center 16+lm-> kk=2*lm+1
        union { unsigned u32; half_t h[2]; } pk;
        pk.h[0] = (half_t)p0;
        pk.h[1] = (half_t)p1;
        *(unsigned*)(Plds + (rt * 16 + l4 * 4 + j) * 40 + lm * 2) = pk.u32;
      }
      // ---- P back as A-operand (same-wave LDS, in-order via lgkmcnt)
      f16x8 pa = *(const f16x8*)(Plds + (rt * 16 + lm) * 40 + l4 * 8);
      // ---- PV (k order matches Vswz interleave) + row-sum via ones column
#pragma unroll
      for (int u = 0; u < 8; ++u)
        O[rt][u] = __builtin_amdgcn_mfma_f32_16x16x32_f16(pa, vb[u], O[rt][u], 0, 0, 0);
      L[rt] = __builtin_amdgcn_mfma_f32_16x16x32_f16(pa, ones, L[rt], 0, 0, 0);
    }
  }

  // ---- epilogue: normalize (row sum = col 0 of L tile, lanes lm==0)
#pragma unroll
  for (int rt = 0; rt < 4; ++rt) {
#pragma unroll
    for (int j = 0; j < 4; ++j) {
      float lv = __shfl(L[rt][j], l & 48);  // broadcast from lane 16*l4
      float inv = 1.0f / fmaxf(lv, 1e-30f);
      int row = rowbase + rt * 16 + l4 * 4 + j;
      float* po = out + row * DOUT + hb * 128 + lm;
#pragma unroll
      for (int u = 0; u < 8; ++u) po[u * 16] = O[rt][u][j] * inv;
    }
  }
}

extern "C" void kernel_launch(void* const* d_in, const int* in_sizes, int n_in,
                              void* d_out, int out_size, void* d_ws, size_t ws_size,
                              hipStream_t stream) {
  const float* x = (const float*)d_in[0];
  const float* ctrs = (const float*)d_in[1];
  const float* values = (const float*)d_in[2];
  const float* s = (const float*)d_in[3];
  float* out = (float*)d_out;
  char* ws = (char*)d_ws;

  hipLaunchKernelGGL(precompute_kernel, dim3(256), dim3(256), 0, stream,
                     ctrs, values, s, ws);
  hipLaunchKernelGGL(attn_kernel, dim3(2048), dim3(64), 0, stream,
                     x, s, ws, out);
}